// Round 1
// baseline (33.465 us; speedup 1.0000x reference)
//
#include <hip/hip_runtime.h>
#include <hip/hip_bf16.h>
#include <math.h>

// RoIPooling2D: x (1, 256, 64, 64) fp32, rois (1, 512, 4) int32 [rx, ry, rw, rh]
// out (512, 256, 7, 7) fp32.
// Per roi: dh = rh/7, dw = rw/7; out[n,c,kb,jb] = max over t<dh, s<dw of
//   x[c, clip(ry + dh*kb + t), clip(rx + dw*jb + s)]

#define C_DIM 256
#define H_DIM 64
#define W_DIM 64
#define OUTH 7
#define OUTW 7

__global__ __launch_bounds__(256) void roipool_kernel(
    const float* __restrict__ x,
    const int* __restrict__ rois,
    float* __restrict__ out,
    int total)
{
    int idx = blockIdx.x * blockDim.x + threadIdx.x;
    if (idx >= total) return;

    int jb = idx % OUTW;
    int kb = (idx / OUTW) % OUTH;
    int c  = (idx / (OUTW * OUTH)) % C_DIM;
    int n  = idx / (OUTW * OUTH * C_DIM);

    const int* roi = rois + n * 4;
    int rx = roi[0];
    int ry = roi[1];
    int rw = roi[2];
    int rh = roi[3];

    int dh = rh / OUTH;   // in [1, 4]
    int dw = rw / OUTW;   // in [1, 4]

    int r0 = ry + dh * kb;
    int c0 = rx + dw * jb;

    const float* f = x + c * (H_DIM * W_DIM);

    float m = -INFINITY;
    for (int t = 0; t < dh; ++t) {
        int r = r0 + t;
        r = (r < 0) ? 0 : (r > H_DIM - 1 ? H_DIM - 1 : r);
        const float* row = f + r * W_DIM;
        for (int s = 0; s < dw; ++s) {
            int cc = c0 + s;
            cc = (cc < 0) ? 0 : (cc > W_DIM - 1 ? W_DIM - 1 : cc);
            m = fmaxf(m, row[cc]);
        }
    }
    out[idx] = m;
}

extern "C" void kernel_launch(void* const* d_in, const int* in_sizes, int n_in,
                              void* d_out, int out_size, void* d_ws, size_t ws_size,
                              hipStream_t stream) {
    const float* x    = (const float*)d_in[0];
    const int*   rois = (const int*)d_in[1];
    float*       out  = (float*)d_out;

    int total = out_size;  // 512 * 256 * 7 * 7
    int block = 256;
    int grid = (total + block - 1) / block;
    roipool_kernel<<<grid, block, 0, stream>>>(x, rois, out, total);
}

// Round 2
// 24.840 us; speedup vs baseline: 1.3472x; 1.3472x over previous
//
#include <hip/hip_runtime.h>
#include <hip/hip_bf16.h>
#include <math.h>

// RoIPooling2D: x (1, 256, 64, 64) fp32, rois (1, 512, 4) int32 [rx, ry, rw, rh]
// out (512, 256, 7, 7) fp32.
// dh = rh/7, dw = rw/7 (both in [1,4] since rw,rh in [7,28]).
// out[n,c,kb,jb] = max over t<dh, s<dw of x[c, ry + dh*kb + t, rx + dw*jb + s]
// Index ranges: ry,rx <= 35, so max row/col = 35 + 4*6 + 3 = 62 < 64 -> clamps never fire.
//
// Strategy:
//  - block = (c, group of 128 sorted roi-positions); grid = 256 c * 4 groups.
//  - stage x[c] (16 KB) into LDS with stride-65 row padding (bank = (row+col)%32).
//  - sort rois by class (dh-1)*4+(dw-1) so each wave sees uniform loop trips
//    (counting sort via ballot/popc, computed redundantly per block by wave 0
//    while waves 1-3 stage the slab -- deterministic, no atomics).
//  - thread = (sorted roi, kb): computes 7 jb-outputs, 7 contiguous stores.

#define NROIS 512
#define SLAB_STRIDE 65   // 64 + 1 pad: bank = (row + col) % 32

__global__ __launch_bounds__(256) void roipool_kernel(
    const float* __restrict__ x,
    const int*   __restrict__ rois,
    float*       __restrict__ out)
{
    __shared__ float          slab[64 * SLAB_STRIDE];   // 16640 B
    __shared__ int4           sroi[NROIS];              //  8192 B
    __shared__ unsigned short sorder[NROIS];            //  1024 B

    const int bid = blockIdx.x;
    const int c   = bid & 255;   // channel
    const int g   = bid >> 8;    // roi group 0..3 (128 sorted positions each)
    const int tid = threadIdx.x;

    if (tid < 64) {
        // ---- wave 0: deterministic counting sort of roi indices by (dh,dw) class
        const int lane = tid;
        const unsigned long long ltmask = (1ull << lane) - 1ull;
        int clsv[8];
        #pragma unroll
        for (int ch = 0; ch < 8; ++ch) {
            int n  = ch * 64 + lane;
            int rw = rois[n * 4 + 2];
            int rh = rois[n * 4 + 3];
            clsv[ch] = (rh / 7 - 1) * 4 + (rw / 7 - 1);   // 0..15
        }
        int start[16];
        {
            int cnt[16];
            #pragma unroll
            for (int k = 0; k < 16; ++k) cnt[k] = 0;
            #pragma unroll
            for (int ch = 0; ch < 8; ++ch) {
                #pragma unroll
                for (int k = 0; k < 16; ++k)
                    cnt[k] += __popcll(__ballot(clsv[ch] == k));
            }
            int acc = 0;
            #pragma unroll
            for (int k = 0; k < 16; ++k) { start[k] = acc; acc += cnt[k]; }
        }
        #pragma unroll
        for (int ch = 0; ch < 8; ++ch) {
            int n = ch * 64 + lane;
            #pragma unroll
            for (int k = 0; k < 16; ++k) {
                unsigned long long m = __ballot(clsv[ch] == k);
                if (clsv[ch] == k)
                    sorder[start[k] + __popcll(m & ltmask)] = (unsigned short)n;
                start[k] += __popcll(m);
            }
        }
    } else {
        // ---- waves 1-3: stage channel slab (float4 global loads, padded LDS rows)
        const float4* xc4 = (const float4*)(x + (size_t)c * 4096);
        for (int i4 = tid - 64; i4 < 1024; i4 += 192) {
            float4 v = xc4[i4];
            int base = (i4 >> 4) * SLAB_STRIDE + ((i4 & 15) << 2);
            slab[base + 0] = v.x;
            slab[base + 1] = v.y;
            slab[base + 2] = v.z;
            slab[base + 3] = v.w;
        }
        // stage rois as int4
        const int4* r4 = (const int4*)rois;
        for (int i = tid - 64; i < NROIS; i += 192) sroi[i] = r4[i];
    }
    __syncthreads();

    // ---- compute: thread = (sorted position, kb) -> 7 outputs
    for (int w = tid; w < 128 * 7; w += 256) {
        unsigned int pl = (unsigned int)w / 7u;
        int kb = w - (int)pl * 7;
        int n  = sorder[g * 128 + pl];
        int4 r = sroi[n];
        int rx = r.x, ry = r.y;
        int dw = r.z / 7;    // 1..4
        int dh = r.w / 7;    // 1..4

        int a0 = (ry + dh * kb) * SLAB_STRIDE + rx;
        float m0 = -INFINITY, m1 = -INFINITY, m2 = -INFINITY, m3 = -INFINITY,
              m4 = -INFINITY, m5 = -INFINITY, m6 = -INFINITY;
        for (int t = 0; t < dh; ++t) {
            int ra = a0 + t * SLAB_STRIDE;
            for (int s = 0; s < dw; ++s) {
                int a = ra + s;
                m0 = fmaxf(m0, slab[a]);
                m1 = fmaxf(m1, slab[a + dw]);
                m2 = fmaxf(m2, slab[a + 2 * dw]);
                m3 = fmaxf(m3, slab[a + 3 * dw]);
                m4 = fmaxf(m4, slab[a + 4 * dw]);
                m5 = fmaxf(m5, slab[a + 5 * dw]);
                m6 = fmaxf(m6, slab[a + 6 * dw]);
            }
        }
        float* op = out + ((size_t)n * 256 + c) * 49 + kb * 7;
        op[0] = m0; op[1] = m1; op[2] = m2; op[3] = m3;
        op[4] = m4; op[5] = m5; op[6] = m6;
    }
}

extern "C" void kernel_launch(void* const* d_in, const int* in_sizes, int n_in,
                              void* d_out, int out_size, void* d_ws, size_t ws_size,
                              hipStream_t stream) {
    const float* x    = (const float*)d_in[0];
    const int*   rois = (const int*)d_in[1];
    float*       out  = (float*)d_out;

    // grid: 4 roi-groups (bid>>8) x 256 channels (bid&255)
    roipool_kernel<<<1024, 256, 0, stream>>>(x, rois, out);
}

// Round 3
// 24.285 us; speedup vs baseline: 1.3780x; 1.0229x over previous
//
#include <hip/hip_runtime.h>
#include <hip/hip_bf16.h>
#include <math.h>

// RoIPooling2D: x (1, 256, 64, 64) fp32, rois (1, 512, 4) int32 [rx, ry, rw, rh]
// out (512, 256, 7, 7) fp32.
// dh = rh/7, dw = rw/7 (both in [1,4] since rw,rh in [7,28]).
// out[n,c,kb,jb] = max over t<dh, s<dw of x[c, ry + dh*kb + t, rx + dw*jb + s]
// ry,rx <= 35 -> max index 35 + 4*6 + 3 = 62 < 64 -> clamps never fire.
//
// Strategy (round 3):
//  - grid = 512 blocks = (roi-half g, channel c); block = 448 threads (7 waves).
//  - stage x[c] (16 KB) into LDS, stride-65 padded rows.
//  - per-block counting sort of all 512 rois by class (dh-1)*4+(dw-1) (wave 0,
//    ballot/popc, deterministic) while waves 1..6 stage.
//  - thread = (sorted position, kb) -> 7 outputs; 1792 items / 448 = exactly 4
//    rounds. Sorted order makes waves class-uniform -> wave-uniform switch into
//    template<DH,DW> fully-unrolled bodies: constant LDS offsets (ds_read2
//    merging, zero dynamic address math).

#define NROIS 512
#define SLAB_STRIDE 65   // 64 + 1 pad

template<int DH, int DW>
__device__ __forceinline__ void pool_body(const float* __restrict__ slab,
                                          int ry, int rx, int kb,
                                          float m[7])
{
    const int a0 = (ry + DH * kb) * SLAB_STRIDE + rx;
    #pragma unroll
    for (int t = 0; t < DH; ++t) {
        #pragma unroll
        for (int j = 0; j < 7 * DW; ++j) {
            m[j / DW] = fmaxf(m[j / DW], slab[a0 + t * SLAB_STRIDE + j]);
        }
    }
}

__global__ __launch_bounds__(448) void roipool_kernel(
    const float* __restrict__ x,
    const int*   __restrict__ rois,
    float*       __restrict__ out)
{
    __shared__ float          slab[64 * SLAB_STRIDE];   // 16640 floats = 66560 B
    __shared__ int4           sroi[NROIS];              //  8192 B
    __shared__ unsigned short sorder[NROIS];            //  1024 B

    const int bid = blockIdx.x;
    const int c   = bid & 255;   // channel
    const int g   = bid >> 8;    // roi half: 0 or 1 (256 sorted positions each)
    const int tid = threadIdx.x;

    if (tid < 64) {
        // ---- wave 0: deterministic counting sort by (dh,dw) class
        const int lane = tid;
        const unsigned long long ltmask = (1ull << lane) - 1ull;
        int clsv[8];
        #pragma unroll
        for (int ch = 0; ch < 8; ++ch) {
            int n  = ch * 64 + lane;
            int rw = rois[n * 4 + 2];
            int rh = rois[n * 4 + 3];
            clsv[ch] = (rh / 7 - 1) * 4 + (rw / 7 - 1);   // 0..15
        }
        int start[16];
        {
            int cnt[16];
            #pragma unroll
            for (int k = 0; k < 16; ++k) cnt[k] = 0;
            #pragma unroll
            for (int ch = 0; ch < 8; ++ch) {
                #pragma unroll
                for (int k = 0; k < 16; ++k)
                    cnt[k] += __popcll(__ballot(clsv[ch] == k));
            }
            int acc = 0;
            #pragma unroll
            for (int k = 0; k < 16; ++k) { start[k] = acc; acc += cnt[k]; }
        }
        #pragma unroll
        for (int ch = 0; ch < 8; ++ch) {
            int n = ch * 64 + lane;
            #pragma unroll
            for (int k = 0; k < 16; ++k) {
                unsigned long long m = __ballot(clsv[ch] == k);
                if (clsv[ch] == k)
                    sorder[start[k] + __popcll(m & ltmask)] = (unsigned short)n;
                start[k] += __popcll(m);
            }
        }
    } else {
        // ---- waves 1..6: stage channel slab + rois
        const float4* xc4 = (const float4*)(x + (size_t)c * 4096);
        for (int i4 = tid - 64; i4 < 1024; i4 += 384) {
            float4 v = xc4[i4];
            int base = (i4 >> 4) * SLAB_STRIDE + ((i4 & 15) << 2);
            slab[base + 0] = v.x;
            slab[base + 1] = v.y;
            slab[base + 2] = v.z;
            slab[base + 3] = v.w;
        }
        const int4* r4 = (const int4*)rois;
        for (int i = tid - 64; i < NROIS; i += 384) sroi[i] = r4[i];
    }
    __syncthreads();

    // ---- compute: 1792 items (256 rois x 7 kb) / 448 threads = 4 rounds exact
    #pragma unroll
    for (int r = 0; r < 4; ++r) {
        int item = tid + r * 448;
        unsigned int pl = (unsigned int)item / 7u;
        int kb = item - (int)pl * 7;
        int n  = sorder[g * 256 + pl];
        int4 roi = sroi[n];
        const int rx = roi.x, ry = roi.y;
        const int dw = roi.z / 7;    // 1..4
        const int dh = roi.w / 7;    // 1..4
        const int cls = (dh - 1) * 4 + (dw - 1);

        float m[7];
        #pragma unroll
        for (int j = 0; j < 7; ++j) m[j] = -INFINITY;

        // Sorted order -> waves are (nearly always) class-uniform; switch is a
        // wave-uniform branch into a fully-unrolled constant-offset body.
        switch (cls) {
            case  0: pool_body<1,1>(slab, ry, rx, kb, m); break;
            case  1: pool_body<1,2>(slab, ry, rx, kb, m); break;
            case  2: pool_body<1,3>(slab, ry, rx, kb, m); break;
            case  3: pool_body<1,4>(slab, ry, rx, kb, m); break;
            case  4: pool_body<2,1>(slab, ry, rx, kb, m); break;
            case  5: pool_body<2,2>(slab, ry, rx, kb, m); break;
            case  6: pool_body<2,3>(slab, ry, rx, kb, m); break;
            case  7: pool_body<2,4>(slab, ry, rx, kb, m); break;
            case  8: pool_body<3,1>(slab, ry, rx, kb, m); break;
            case  9: pool_body<3,2>(slab, ry, rx, kb, m); break;
            case 10: pool_body<3,3>(slab, ry, rx, kb, m); break;
            case 11: pool_body<3,4>(slab, ry, rx, kb, m); break;
            case 12: pool_body<4,1>(slab, ry, rx, kb, m); break;
            case 13: pool_body<4,2>(slab, ry, rx, kb, m); break;
            case 14: pool_body<4,3>(slab, ry, rx, kb, m); break;
            default: pool_body<4,4>(slab, ry, rx, kb, m); break;
        }

        float* op = out + ((size_t)n * 256 + c) * 49 + kb * 7;
        op[0] = m[0]; op[1] = m[1]; op[2] = m[2]; op[3] = m[3];
        op[4] = m[4]; op[5] = m[5]; op[6] = m[6];
    }
}

extern "C" void kernel_launch(void* const* d_in, const int* in_sizes, int n_in,
                              void* d_out, int out_size, void* d_ws, size_t ws_size,
                              hipStream_t stream) {
    const float* x    = (const float*)d_in[0];
    const int*   rois = (const int*)d_in[1];
    float*       out  = (float*)d_out;

    // grid: 2 roi-halves (bid>>8) x 256 channels (bid&255)
    roipool_kernel<<<512, 448, 0, stream>>>(x, rois, out);
}

// Round 4
// 22.631 us; speedup vs baseline: 1.4788x; 1.0731x over previous
//
#include <hip/hip_runtime.h>
#include <hip/hip_bf16.h>
#include <math.h>

// RoIPooling2D: x (1, 256, 64, 64) fp32, rois (1, 512, 4) int32 [rx, ry, rw, rh]
// out (512, 256, 7, 7) fp32.
// dh = rh/7, dw = rw/7 (both in [1,4] since rw,rh in [7,28]).
// out[n,c,kb,jb] = max over t<dh, s<dw of x[c, ry + dh*kb + t, rx + dw*jb + s]
// ry,rx <= 35 -> max index 62 < 64 -> clamps never fire.
//
// Round 4 strategy:
//  - kernel1 (1 block): counting-sort rois by class (dh-1)*4+(dw-1) via LDS
//    atomics; write sorted descriptors int4{rx, ry, cls, n} to d_ws. Within-
//    class order is arbitrary (atomics) but the OUTPUT is order-invariant:
//    each roi is computed exactly once and written to its own out[n] slot.
//  - kernel2: grid 512 = (roi-half g, channel c); 448 threads (7 waves).
//    * stage x[c] (16 KB) into LDS slab, stride-65 rows (bank=(row+col)%32).
//    * thread = (sorted pos, kb) -> 7 outputs via wave-uniform switch into
//      template<DH,DW> constant-offset bodies (rois sorted -> uniform waves).
//    * STORES COALESCED: each round (64 rois) writes 64x49 floats to LDS
//      outbuf (addr=7*tid+j, stride-7 -> 2 lanes/bank, conflict-free), then
//      cooperative copy to global in contiguous 49-float runs.

#define SLAB_STRIDE 65

// ---------------- kernel 1: sort ----------------
__global__ __launch_bounds__(512) void roi_sort_kernel(
    const int* __restrict__ rois, int4* __restrict__ sdesc)
{
    __shared__ int start[16];
    const int tid = threadIdx.x;
    if (tid < 16) start[tid] = 0;
    __syncthreads();
    const int4 r = ((const int4*)rois)[tid];
    const int dw = r.z / 7, dh = r.w / 7;          // 1..4
    const int cls = (dh - 1) * 4 + (dw - 1);       // 0..15
    atomicAdd(&start[cls], 1);
    __syncthreads();
    if (tid == 0) {
        int acc = 0;
        #pragma unroll
        for (int k = 0; k < 16; ++k) { int cnt = start[k]; start[k] = acc; acc += cnt; }
    }
    __syncthreads();
    const int pos = atomicAdd(&start[cls], 1);
    sdesc[pos] = make_int4(r.x, r.y, cls, tid);
}

// ---------------- kernel 2: pool ----------------
template<int DH, int DW>
__device__ __forceinline__ void pool_body(const float* __restrict__ slab,
                                          int ry, int rx, int kb,
                                          float m[7])
{
    const int a0 = (ry + DH * kb) * SLAB_STRIDE + rx;
    #pragma unroll
    for (int t = 0; t < DH; ++t) {
        #pragma unroll
        for (int j = 0; j < 7 * DW; ++j) {
            m[j / DW] = fmaxf(m[j / DW], slab[a0 + t * SLAB_STRIDE + j]);
        }
    }
}

__global__ __launch_bounds__(448) void roipool_kernel(
    const float* __restrict__ x,
    const int4*  __restrict__ sdesc,
    float*       __restrict__ out)
{
    __shared__ float slab[64 * SLAB_STRIDE];   // 66560 B
    __shared__ float outbuf[64 * 49];          // 12544 B
    __shared__ int   snn[256];                 //  1024 B   total 80128 B -> 2 blocks/CU

    const int bid = blockIdx.x;
    const int c   = bid & 255;   // channel
    const int g   = bid >> 8;    // roi half: 0 or 1
    const int tid = threadIdx.x;

    // ---- stage channel slab (float4 loads, padded LDS rows)
    const float4* xc4 = (const float4*)(x + (size_t)c * 4096);
    #pragma unroll
    for (int rr = 0; rr < 3; ++rr) {
        int i4 = tid + rr * 448;
        if (i4 < 1024) {
            float4 v = xc4[i4];
            int base = (i4 >> 4) * SLAB_STRIDE + ((i4 & 15) << 2);
            slab[base + 0] = v.x;
            slab[base + 1] = v.y;
            slab[base + 2] = v.z;
            slab[base + 3] = v.w;
        }
    }

    // ---- preload this thread's 4 round-descriptors (overlaps staging latency)
    const unsigned q0 = (unsigned)tid / 7u;        // 0..63 (local roi in round)
    const int kb = tid - (int)q0 * 7;              // 0..6
    int4 dsc[4];
    #pragma unroll
    for (int r = 0; r < 4; ++r)
        dsc[r] = sdesc[g * 256 + r * 64 + (int)q0];
    if (kb == 0) {
        #pragma unroll
        for (int r = 0; r < 4; ++r)
            snn[r * 64 + q0] = dsc[r].w;
    }
    __syncthreads();

    // ---- 4 rounds x 64 rois: compute -> LDS outbuf -> coalesced global copy
    #pragma unroll
    for (int r = 0; r < 4; ++r) {
        const int4 d = dsc[r];
        float m[7];
        #pragma unroll
        for (int j = 0; j < 7; ++j) m[j] = -INFINITY;

        switch (d.z) {
            case  0: pool_body<1,1>(slab, d.y, d.x, kb, m); break;
            case  1: pool_body<1,2>(slab, d.y, d.x, kb, m); break;
            case  2: pool_body<1,3>(slab, d.y, d.x, kb, m); break;
            case  3: pool_body<1,4>(slab, d.y, d.x, kb, m); break;
            case  4: pool_body<2,1>(slab, d.y, d.x, kb, m); break;
            case  5: pool_body<2,2>(slab, d.y, d.x, kb, m); break;
            case  6: pool_body<2,3>(slab, d.y, d.x, kb, m); break;
            case  7: pool_body<2,4>(slab, d.y, d.x, kb, m); break;
            case  8: pool_body<3,1>(slab, d.y, d.x, kb, m); break;
            case  9: pool_body<3,2>(slab, d.y, d.x, kb, m); break;
            case 10: pool_body<3,3>(slab, d.y, d.x, kb, m); break;
            case 11: pool_body<3,4>(slab, d.y, d.x, kb, m); break;
            case 12: pool_body<4,1>(slab, d.y, d.x, kb, m); break;
            case 13: pool_body<4,2>(slab, d.y, d.x, kb, m); break;
            case 14: pool_body<4,3>(slab, d.y, d.x, kb, m); break;
            default: pool_body<4,4>(slab, d.y, d.x, kb, m); break;
        }

        // write 7 results to LDS: addr = 7*tid + j -> stride-7 across lanes,
        // 2 lanes/bank -> conflict-free.
        #pragma unroll
        for (int j = 0; j < 7; ++j) outbuf[tid * 7 + j] = m[j];
        __syncthreads();

        // cooperative coalesced store: 3136 floats = 64 rois x 49 contiguous.
        #pragma unroll
        for (int j = 0; j < 7; ++j) {
            int idx = j * 448 + tid;
            unsigned q = (unsigned)idx / 49u;
            int k = idx - (int)q * 49;
            int n = snn[r * 64 + (int)q];
            out[((size_t)(n * 256 + c)) * 49 + k] = outbuf[idx];
        }
        __syncthreads();   // outbuf reused next round
    }
}

extern "C" void kernel_launch(void* const* d_in, const int* in_sizes, int n_in,
                              void* d_out, int out_size, void* d_ws, size_t ws_size,
                              hipStream_t stream) {
    const float* x    = (const float*)d_in[0];
    const int*   rois = (const int*)d_in[1];
    float*       out  = (float*)d_out;
    int4*        sdesc = (int4*)d_ws;   // 512 * 16 B = 8 KB scratch

    roi_sort_kernel<<<1, 512, 0, stream>>>(rois, sdesc);
    // grid: 2 roi-halves (bid>>8) x 256 channels (bid&255)
    roipool_kernel<<<512, 448, 0, stream>>>(x, sdesc, out);
}

// Round 7
// 22.076 us; speedup vs baseline: 1.5159x; 1.0251x over previous
//
#include <hip/hip_runtime.h>
#include <hip/hip_bf16.h>
#include <math.h>

// RoIPooling2D: x (1, 256, 64, 64) fp32, rois (1, 512, 4) int32 [rx, ry, rw, rh]
// out (512, 256, 7, 7) fp32.
// dh = rh/7, dw = rw/7 (both in [1,4] since rw,rh in [7,28]).
// out[n,c,kb,jb] = max over t<dh, s<dw of x[c, ry + dh*kb + t, rx + dw*jb + s]
// rx,ry <= 35 -> max index 62 < 64 -> clamps never fire.
//
// Round 7 = R4's PROVEN two-kernel structure, one minimal change: kernel2 grid
// 512 -> 1024 (roi-QUARTERS instead of halves) so 4 blocks/CU are co-resident
// (28 waves/CU vs 14) to hide LDS latency and barrier bubbles.
//  - kernel1 (1 block): counting-sort rois by class via LDS atomics ->
//    sorted descriptors int4{rx, ry, cls, n} in d_ws (order-invariant output).
//  - kernel2: grid 1024 = (roi-quarter g 0..3, channel c); 448 threads.
//    slab staged in LDS (stride-65), template<DH,DW> wave-uniform bodies,
//    stores coalesced via LDS outbuf transpose.

#define SLAB_STRIDE 65

// ---------------- kernel 1: sort (verbatim from R4, proven) ----------------
__global__ __launch_bounds__(512) void roi_sort_kernel(
    const int* __restrict__ rois, int4* __restrict__ sdesc)
{
    __shared__ int start[16];
    const int tid = threadIdx.x;
    if (tid < 16) start[tid] = 0;
    __syncthreads();
    const int4 r = ((const int4*)rois)[tid];
    const int dw = r.z / 7, dh = r.w / 7;          // 1..4
    const int cls = (dh - 1) * 4 + (dw - 1);       // 0..15
    atomicAdd(&start[cls], 1);
    __syncthreads();
    if (tid == 0) {
        int acc = 0;
        #pragma unroll
        for (int k = 0; k < 16; ++k) { int cnt = start[k]; start[k] = acc; acc += cnt; }
    }
    __syncthreads();
    const int pos = atomicAdd(&start[cls], 1);
    sdesc[pos] = make_int4(r.x, r.y, cls, tid);
}

// ---------------- kernel 2: pool ----------------
template<int DH, int DW>
__device__ __forceinline__ void pool_body(const float* __restrict__ slab,
                                          int ry, int rx, int kb,
                                          float m[7])
{
    const int a0 = (ry + DH * kb) * SLAB_STRIDE + rx;
    #pragma unroll
    for (int t = 0; t < DH; ++t) {
        #pragma unroll
        for (int j = 0; j < 7 * DW; ++j) {
            m[j / DW] = fmaxf(m[j / DW], slab[a0 + t * SLAB_STRIDE + j]);
        }
    }
}

__global__ __launch_bounds__(448) void roipool_kernel(
    const float* __restrict__ x,
    const int4*  __restrict__ sdesc,
    float*       __restrict__ out)
{
    __shared__ float slab[64 * SLAB_STRIDE];   // 16640 B
    __shared__ float outbuf[64 * 49];          // 12544 B
    __shared__ int   snn[128];                 //   512 B  total ~29.7 KB -> 4 blocks/CU

    const int bid = blockIdx.x;
    const int c   = bid & 255;   // channel
    const int g   = bid >> 8;    // roi quarter: 0..3 (128 sorted positions each)
    const int tid = threadIdx.x;

    // ---- stage channel slab (float4 loads, padded LDS rows) [R4 proven]
    const float4* xc4 = (const float4*)(x + (size_t)c * 4096);
    #pragma unroll
    for (int rr = 0; rr < 3; ++rr) {
        int i4 = tid + rr * 448;
        if (i4 < 1024) {
            float4 v = xc4[i4];
            int base = (i4 >> 4) * SLAB_STRIDE + ((i4 & 15) << 2);
            slab[base + 0] = v.x;
            slab[base + 1] = v.y;
            slab[base + 2] = v.z;
            slab[base + 3] = v.w;
        }
    }

    // ---- preload this thread's 2 round-descriptors (overlaps staging latency)
    const unsigned q0 = (unsigned)tid / 7u;        // 0..63 (local roi in round)
    const int kb = tid - (int)q0 * 7;              // 0..6
    int4 dsc[2];
    #pragma unroll
    for (int r = 0; r < 2; ++r)
        dsc[r] = sdesc[g * 128 + r * 64 + (int)q0];
    if (kb == 0) {
        #pragma unroll
        for (int r = 0; r < 2; ++r)
            snn[r * 64 + q0] = dsc[r].w;
    }
    __syncthreads();

    // ---- 2 rounds x 64 rois: compute -> LDS outbuf -> coalesced global copy
    #pragma unroll
    for (int r = 0; r < 2; ++r) {
        const int4 d = dsc[r];
        float m[7];
        #pragma unroll
        for (int j = 0; j < 7; ++j) m[j] = -INFINITY;

        switch (d.z) {   // wave-uniform (sorted)
            case  0: pool_body<1,1>(slab, d.y, d.x, kb, m); break;
            case  1: pool_body<1,2>(slab, d.y, d.x, kb, m); break;
            case  2: pool_body<1,3>(slab, d.y, d.x, kb, m); break;
            case  3: pool_body<1,4>(slab, d.y, d.x, kb, m); break;
            case  4: pool_body<2,1>(slab, d.y, d.x, kb, m); break;
            case  5: pool_body<2,2>(slab, d.y, d.x, kb, m); break;
            case  6: pool_body<2,3>(slab, d.y, d.x, kb, m); break;
            case  7: pool_body<2,4>(slab, d.y, d.x, kb, m); break;
            case  8: pool_body<3,1>(slab, d.y, d.x, kb, m); break;
            case  9: pool_body<3,2>(slab, d.y, d.x, kb, m); break;
            case 10: pool_body<3,3>(slab, d.y, d.x, kb, m); break;
            case 11: pool_body<3,4>(slab, d.y, d.x, kb, m); break;
            case 12: pool_body<4,1>(slab, d.y, d.x, kb, m); break;
            case 13: pool_body<4,2>(slab, d.y, d.x, kb, m); break;
            case 14: pool_body<4,3>(slab, d.y, d.x, kb, m); break;
            default: pool_body<4,4>(slab, d.y, d.x, kb, m); break;
        }

        // write 7 results to LDS: addr = 7*tid + j -> stride-7 across lanes,
        // 2 lanes/bank -> conflict-free.
        #pragma unroll
        for (int j = 0; j < 7; ++j) outbuf[tid * 7 + j] = m[j];
        __syncthreads();

        // cooperative coalesced store: 3136 floats = 64 rois x 49 contiguous.
        #pragma unroll
        for (int j = 0; j < 7; ++j) {
            int idx = j * 448 + tid;
            unsigned q = (unsigned)idx / 49u;
            int k = idx - (int)q * 49;
            int n = snn[r * 64 + (int)q];
            out[((size_t)(n * 256 + c)) * 49 + k] = outbuf[idx];
        }
        __syncthreads();   // outbuf reused next round
    }
}

extern "C" void kernel_launch(void* const* d_in, const int* in_sizes, int n_in,
                              void* d_out, int out_size, void* d_ws, size_t ws_size,
                              hipStream_t stream) {
    const float* x    = (const float*)d_in[0];
    const int*   rois = (const int*)d_in[1];
    float*       out  = (float*)d_out;
    int4*        sdesc = (int4*)d_ws;   // 512 * 16 B = 8 KB scratch

    roi_sort_kernel<<<1, 512, 0, stream>>>(rois, sdesc);
    // grid: 4 roi-quarters (bid>>8) x 256 channels (bid&255)
    roipool_kernel<<<1024, 448, 0, stream>>>(x, sdesc, out);
}